// Round 9
// baseline (9054.700 us; speedup 1.0000x reference)
//
#include <hip/hip_runtime.h>
#include <cstdint>
#include <cstddef>

typedef float f32x4 __attribute__((ext_vector_type(4)));
typedef __bf16 bf16x8 __attribute__((ext_vector_type(8)));
typedef unsigned int u32x4 __attribute__((ext_vector_type(4)));

#define T_STEPS 256
#define HD      1024
#define DHK     2048
#define LDSW_BYTES (128 * 64 * 16)   // 128 K-windows x 64 lanes x 16B = 128 KiB

__device__ __forceinline__ unsigned short f2bf(float f) {
  union { float f; unsigned u; } v; v.f = f;
  unsigned r = v.u + 0x7fffu + ((v.u >> 16) & 1u);  // RNE, inputs finite
  return (unsigned short)(r >> 16);
}
__device__ __forceinline__ float fast_sigmoid(float x) {
  return 1.0f / (1.0f + __expf(-x));
}
__device__ __forceinline__ float fast_tanh(float x) {
  float e = __expf(2.0f * x);
  return (e - 1.0f) / (e + 1.0f);
}
__device__ __forceinline__ f32x4 mfma16(bf16x8 a, bf16x8 b, f32x4 c) {
  return __builtin_amdgcn_mfma_f32_16x16x32_bf16(a, b, c, 0, 0, 0);
}

// ---- coherent (L1/L2-bypass) ops ----
#define LOADB(dst, vofs, base, IMM)                                            \
  asm volatile("global_load_dwordx4 %0, %1, %2 offset:" IMM " sc0 sc1"         \
               : "=v"(dst) : "v"(vofs), "s"(base) : "memory")

// 32 K-window loads along one row: window w at byte offset w*64
#define L32(d, vofs, base)                                                     \
  LOADB(d[0],vofs,base,"0");    LOADB(d[1],vofs,base,"64");                    \
  LOADB(d[2],vofs,base,"128");  LOADB(d[3],vofs,base,"192");                   \
  LOADB(d[4],vofs,base,"256");  LOADB(d[5],vofs,base,"320");                   \
  LOADB(d[6],vofs,base,"384");  LOADB(d[7],vofs,base,"448");                   \
  LOADB(d[8],vofs,base,"512");  LOADB(d[9],vofs,base,"576");                   \
  LOADB(d[10],vofs,base,"640"); LOADB(d[11],vofs,base,"704");                  \
  LOADB(d[12],vofs,base,"768"); LOADB(d[13],vofs,base,"832");                  \
  LOADB(d[14],vofs,base,"896"); LOADB(d[15],vofs,base,"960");                  \
  LOADB(d[16],vofs,base,"1024");LOADB(d[17],vofs,base,"1088");                 \
  LOADB(d[18],vofs,base,"1152");LOADB(d[19],vofs,base,"1216");                 \
  LOADB(d[20],vofs,base,"1280");LOADB(d[21],vofs,base,"1344");                 \
  LOADB(d[22],vofs,base,"1408");LOADB(d[23],vofs,base,"1472");                 \
  LOADB(d[24],vofs,base,"1536");LOADB(d[25],vofs,base,"1600");                 \
  LOADB(d[26],vofs,base,"1664");LOADB(d[27],vofs,base,"1728");                 \
  LOADB(d[28],vofs,base,"1792");LOADB(d[29],vofs,base,"1856");                 \
  LOADB(d[30],vofs,base,"1920");LOADB(d[31],vofs,base,"1984")

#define WAITV0()                                                               \
  do { asm volatile("s_waitcnt vmcnt(0)" ::: "memory");                        \
       __builtin_amdgcn_sched_barrier(0); } while (0)

__device__ __forceinline__ void storec2(void* p, unsigned short v) {
  unsigned vv = v;
  asm volatile("global_store_short %0, %1, off sc0 sc1"
               :: "v"(p), "v"(vv) : "memory");
}
__device__ __forceinline__ void storec4(void* p, unsigned v) {
  asm volatile("global_store_dword %0, %1, off sc0 sc1"
               :: "v"(p), "v"(v) : "memory");
}

// poll 4 consecutive epoch cells (one dwordx4 per lane) until all == tgt
__device__ __forceinline__ void poll4(const unsigned* base, int vofs,
                                      unsigned tgt) {
  while (true) {
    u32x4 e;
    asm volatile("global_load_dwordx4 %0, %1, %2 sc0 sc1"
                 : "=v"(e) : "v"(vofs), "s"(base) : "memory");
    asm volatile("s_waitcnt vmcnt(0)" ::: "memory");
    int ok = (e[0] == tgt) & (e[1] == tgt) & (e[2] == tgt) & (e[3] == tgt);
    if (__all(ok)) break;
    __builtin_amdgcn_s_sleep(1);
  }
  __builtin_amdgcn_sched_barrier(0);
}
// poll a single cell per lane
__device__ __forceinline__ void poll1(const unsigned* base, int vofs,
                                      unsigned tgt) {
  while (true) {
    unsigned e;
    asm volatile("global_load_dword %0, %1, %2 sc0 sc1"
                 : "=v"(e) : "v"(vofs), "s"(base) : "memory");
    asm volatile("s_waitcnt vmcnt(0)" ::: "memory");
    if (__all((int)(e == tgt))) break;
    __builtin_amdgcn_s_sleep(1);
  }
  __builtin_amdgcn_sched_barrier(0);
}

// ---- wave-dataflow persistent kernel: 256 blocks x 4 waves, NO barriers ----
// Block nb: g = nb>>6 (A/B: gate | C: batch-16-group), n0 = (nb&63)*16 cols.
// Each wave owns 16 output rows x 16 cols with FULL-K contraction (no LDS
// reduce). Epoch-cell handshake: produce(data) -> vmcnt(0) -> epoch=t+1.
//   eG  cell (wvA*4 + gate)*64 + n0g   : A-wave published its G 16x16 tile
//   eG2 cell (wvB*4 + gate)*64 + n0g   : B-wave published its G2 tile
//   eH  cell (q*4 + wvC)*64 + n0g      : C-wave published h rows q*16+wvC*4..
__global__ __launch_bounds__(256, 1) void qlstm_persist(
    const unsigned short* __restrict__ Xbf,
    const unsigned short* __restrict__ Wbf,      // [4096][2048]
    const unsigned short* __restrict__ qcw,      // [2][1024][1024]
    const float* __restrict__ bias_cat,          // [4096]
    const float* __restrict__ qcb,               // [2][1024]
    unsigned short* __restrict__ Gbf,            // [256][1024] gate-major
    unsigned short* __restrict__ G2bf,           // [256][1024] gate-major
    unsigned short* __restrict__ hbf,            // [64][1024]
    float* __restrict__ out,
    unsigned* __restrict__ eG, unsigned* __restrict__ eG2,
    unsigned* __restrict__ eH) {
  extern __shared__ char lds_raw[];
  u32x4* lw = (u32x4*)lds_raw;   // [128 win][64 lane] 16B frags

  const int nb = blockIdx.x, tid = threadIdx.x;
  const int wv = tid >> 6, lane = tid & 63;
  const int l15 = lane & 15, l16 = lane >> 4;
  const int l16o = l16 * 8;
  const int g = nb >> 6;            // gate (A,B) / batch-group (C)
  const int n0 = (nb & 63) * 16;
  const int n0g = nb & 63;

  // ---- stage weights into LDS, frag order [win][lane]; wins:
  //   0..31 A-x | 32..63 A-h | 64..95 B | 96..127 C
  {
    const int ls = tid & 63, j0 = tid >> 6;
    const int s15 = ls & 15, s16o = (ls >> 4) * 8;
#pragma unroll
    for (int jj = 0; jj < 32; ++jj) {
      const int win = jj * 4 + j0;
      const unsigned short* src;
      if (win < 32)
        src = Wbf + (size_t)(nb * 16 + s15) * DHK + win * 32 + s16o;
      else if (win < 64)
        src = Wbf + (size_t)(nb * 16 + s15) * DHK + 1024 + (win - 32) * 32 + s16o;
      else if (win < 96)
        src = qcw + (size_t)(n0 + s15) * HD + (win - 64) * 32 + s16o;
      else
        src = qcw + (size_t)HD * HD + (size_t)(n0 + s15) * HD + (win - 96) * 32 + s16o;
      lw[win * 64 + ls] = *(const u32x4*)src;
    }
  }
  __syncthreads();   // only barrier in the kernel

  // per-wave row byte offsets (step-invariant)
  const int vA = ((wv * 16 + l15) * HD + l16o) * 2;              // h rows
  const int vB = ((g * 64 + wv * 16 + l15) * HD + l16o) * 2;     // G rows
  const int crow = (l15 & 3) * 64 + g * 16 + wv * 4 + (l15 >> 2);
  const int vC = (crow * HD + l16o) * 2;                         // G2 rows
  const int veH = (wv * 256 + lane * 4) * 4;    // A polls 4 cells
  const int veG = ((wv * 4 + g) * 64 + lane) * 4;  // B polls 1 cell
  const int veG2 = (g * 256 + lane * 4) * 4;    // C polls 4 cells

  const float bA = bias_cat[nb * 16 + l15];
  const float bB = qcb[n0 + l15];
  const float bC = qcb[HD + n0 + l15];
  const int colA = n0 + l15;
  const int batchC = g * 16 + wv * 4 + l16;     // C's batch per thread

  float c_reg = 0.0f;
  bf16x8 d[32];

  for (int t = 0; t < T_STEPS; ++t) {
    // ================= phase A =================
    {
      f32x4 a0 = {}, a1 = {};
      // x-part (cached reads, recurrence-independent: runs before the poll)
      const unsigned short* xb = Xbf + (size_t)t * (64 * HD);
#pragma unroll
      for (int w = 0; w < 32; w += 2) {
        bf16x8 x0 = *(const bf16x8*)&xb[(size_t)(wv * 16 + l15) * HD + w * 32 + l16o];
        bf16x8 x1 = *(const bf16x8*)&xb[(size_t)(wv * 16 + l15) * HD + (w + 1) * 32 + l16o];
        a0 = mfma16(x0, *(const bf16x8*)&lw[w * 64 + lane], a0);
        a1 = mfma16(x1, *(const bf16x8*)&lw[(w + 1) * 64 + lane], a1);
      }
      poll4(eH, veH, (unsigned)t);              // h(t-1) tiles for our rows
      L32(d, vA, hbf);
      WAITV0();
#pragma unroll
      for (int w = 0; w < 32; w += 2) {
        a0 = mfma16(d[w],     *(const bf16x8*)&lw[(32 + w) * 64 + lane], a0);
        a1 = mfma16(d[w + 1], *(const bf16x8*)&lw[(33 + w) * 64 + lane], a1);
      }
      f32x4 acc = a0 + a1;
#pragma unroll
      for (int i = 0; i < 4; ++i) {
        const int row = g * 64 + wv * 16 + l16 * 4 + i;
        float v = acc[i] + bA;
        v = (g == 2) ? fast_tanh(v) : fast_sigmoid(v);
        storec2(&Gbf[(size_t)row * HD + colA], f2bf(v));
      }
      asm volatile("s_waitcnt vmcnt(0)" ::: "memory");
      if (lane == 0) storec4(&eG[(wv * 4 + g) * 64 + n0g], (unsigned)(t + 1));
    }
    // ================= phase B =================
    {
      poll1(eG, veG, (unsigned)(t + 1));
      L32(d, vB, Gbf);
      WAITV0();
      f32x4 a0 = {}, a1 = {};
#pragma unroll
      for (int w = 0; w < 32; w += 2) {
        a0 = mfma16(d[w],     *(const bf16x8*)&lw[(64 + w) * 64 + lane], a0);
        a1 = mfma16(d[w + 1], *(const bf16x8*)&lw[(65 + w) * 64 + lane], a1);
      }
      f32x4 acc = a0 + a1;
#pragma unroll
      for (int i = 0; i < 4; ++i) {
        const int row = g * 64 + wv * 16 + l16 * 4 + i;
        storec2(&G2bf[(size_t)row * HD + colA], f2bf(fast_tanh(acc[i] + bB)));
      }
      asm volatile("s_waitcnt vmcnt(0)" ::: "memory");
      if (lane == 0) storec4(&eG2[(wv * 4 + g) * 64 + n0g], (unsigned)(t + 1));
    }
    // ================= phase C + cell update =================
    {
      poll4(eG2, veG2, (unsigned)(t + 1));
      L32(d, vC, G2bf);
      WAITV0();
      f32x4 a0 = {}, a1 = {};
#pragma unroll
      for (int w = 0; w < 32; w += 2) {
        a0 = mfma16(d[w],     *(const bf16x8*)&lw[(96 + w) * 64 + lane], a0);
        a1 = mfma16(d[w + 1], *(const bf16x8*)&lw[(97 + w) * 64 + lane], a1);
      }
      f32x4 acc = a0 + a1;
      float gv[4];
#pragma unroll
      for (int i = 0; i < 4; ++i) gv[i] = fast_tanh(acc[i] + bC);
      c_reg = gv[0] * c_reg + gv[1] * gv[2];
      const float h_new = gv[3] * fast_tanh(c_reg);
      storec2(&hbf[(size_t)batchC * HD + colA], f2bf(h_new));
      asm volatile("s_waitcnt vmcnt(0)" ::: "memory");
      if (lane == 0) storec4(&eH[(g * 4 + wv) * 64 + n0g], (unsigned)(t + 1));
      // off the critical path (cached):
      out[(size_t)t * (64 * HD) + batchC * HD + colA] = h_new;
      if (t == T_STEPS - 1) {
        out[(size_t)T_STEPS * (64 * HD) + batchC * HD + colA] = h_new;
        out[(size_t)T_STEPS * (64 * HD) + 64 * HD + batchC * HD + colA] = c_reg;
      }
    }
  }
}

// ---- prep kernels ----------------------------------------------------------
__global__ void xconv_kernel(const float* __restrict__ x,
                             unsigned short* __restrict__ xbf, int n4) {
  int idx = blockIdx.x * blockDim.x + threadIdx.x;
  int stride = gridDim.x * blockDim.x;
  for (int i = idx; i < n4; i += stride) {
    float4 v = ((const float4*)x)[i];
    ushort4 o;
    o.x = f2bf(v.x); o.y = f2bf(v.y); o.z = f2bf(v.z); o.w = f2bf(v.w);
    ((ushort4*)xbf)[i] = o;
  }
}

__global__ void wconv_kernel(const float* __restrict__ Wf, const float* __restrict__ Wi,
                             const float* __restrict__ Wu, const float* __restrict__ Wo,
                             const float* __restrict__ bfv, const float* __restrict__ biv,
                             const float* __restrict__ buv, const float* __restrict__ bov,
                             unsigned short* __restrict__ Wbf, float* __restrict__ bias_cat) {
  const int n = blockIdx.x;                 // 0..4095
  const int gate = n >> 10, r = n & 1023;
  const float* W = gate == 0 ? Wf : gate == 1 ? Wi : gate == 2 ? Wu : Wo;
  const float* src = W + (size_t)r * DHK;
  unsigned short* dst = Wbf + (size_t)n * DHK;
  for (int k = threadIdx.x; k < DHK; k += 256) dst[k] = f2bf(src[k]);
  if (threadIdx.x == 0) {
    const float* bsrc = gate == 0 ? bfv : gate == 1 ? biv : gate == 2 ? buv : bov;
    bias_cat[n] = bsrc[r];
  }
}

__global__ void qcw_kernel(const float* __restrict__ qcv, const float* __restrict__ qcg,
                           unsigned short* __restrict__ qcw) {
  const int row = blockIdx.x * 4 + (threadIdx.x >> 6);  // 0..2047 (= d*1024+o)
  const int lane = threadIdx.x & 63;
  const float* v = qcv + (size_t)row * HD;
  float ss = 0.0f;
#pragma unroll
  for (int j = 0; j < 16; ++j) { float a = v[j * 64 + lane]; ss += a * a; }
#pragma unroll
  for (int off = 32; off > 0; off >>= 1) ss += __shfl_xor(ss, off);
  const float scale = qcg[row] / sqrtf(ss);
#pragma unroll
  for (int j = 0; j < 16; ++j)
    qcw[(size_t)row * HD + j * 64 + lane] = f2bf(v[j * 64 + lane] * scale);
}

__global__ void init_state_kernel(unsigned short* __restrict__ hbf,
                                  unsigned* __restrict__ epochs) {
  int i = blockIdx.x * blockDim.x + threadIdx.x;  // 65536 launched
  hbf[i] = 0;
  if (i < 3072) epochs[i] = 0;                    // eG, eG2, eH
}

// ---- launcher --------------------------------------------------------------
extern "C" void kernel_launch(void* const* d_in, const int* in_sizes, int n_in,
                              void* d_out, int out_size, void* d_ws, size_t ws_size,
                              hipStream_t stream) {
  const float* x   = (const float*)d_in[0];
  const float* Wf  = (const float*)d_in[1];
  const float* bfv = (const float*)d_in[2];
  const float* Wi  = (const float*)d_in[3];
  const float* biv = (const float*)d_in[4];
  const float* Wu  = (const float*)d_in[5];
  const float* buv = (const float*)d_in[6];
  const float* Wo  = (const float*)d_in[7];
  const float* bov = (const float*)d_in[8];
  const float* qcv = (const float*)d_in[9];
  const float* qcg = (const float*)d_in[10];
  const float* qcb = (const float*)d_in[11];
  float* out = (float*)d_out;

  char* p = (char*)d_ws;
  auto alloc = [&](size_t bytes) {
    char* r = p; p += (bytes + 255) & ~(size_t)255; return r;
  };
  unsigned short* Xbf  = (unsigned short*)alloc((size_t)T_STEPS * 64 * HD * 2);
  unsigned short* Wbf  = (unsigned short*)alloc((size_t)4096 * DHK * 2);
  unsigned short* qcw  = (unsigned short*)alloc((size_t)2 * HD * HD * 2);
  float* bias_cat      = (float*)alloc((size_t)4096 * 4);
  unsigned short* Gbf  = (unsigned short*)alloc((size_t)256 * HD * 2);
  unsigned short* G2bf = (unsigned short*)alloc((size_t)256 * HD * 2);
  unsigned short* hbf  = (unsigned short*)alloc((size_t)64 * HD * 2);
  unsigned* epochs     = (unsigned*)alloc(3072 * 4);   // eG | eG2 | eH

  static int lds_set = 0;
  if (!lds_set) {
    hipFuncSetAttribute((const void*)qlstm_persist,
                        hipFuncAttributeMaxDynamicSharedMemorySize, LDSW_BYTES);
    lds_set = 1;
  }

  init_state_kernel<<<256, 256, 0, stream>>>(hbf, epochs);
  xconv_kernel<<<2048, 256, 0, stream>>>(x, Xbf, T_STEPS * 64 * HD / 4);
  wconv_kernel<<<4096, 256, 0, stream>>>(Wf, Wi, Wu, Wo, bfv, biv, buv, bov,
                                         Wbf, bias_cat);
  qcw_kernel<<<512, 256, 0, stream>>>(qcv, qcg, qcw);

  qlstm_persist<<<256, 256, LDSW_BYTES, stream>>>(
      Xbf, Wbf, qcw, bias_cat, qcb, Gbf, G2bf, hbf, out,
      epochs, epochs + 1024, epochs + 2048);
}